// Round 6
// baseline (179.540 us; speedup 1.0000x reference)
//
#include <hip/hip_runtime.h>
#include <hip/hip_bf16.h>
#include <stdint.h>

// Problem constants
#define NB 2
#define NS 2048
#define ND 1024
#define NH 16
#define NDK 64
#define NM (NB*NS)   // 4096 rows

using bf16x8 = __attribute__((ext_vector_type(8))) short;   // 8 bf16 (4 VGPRs)
using f32x4  = __attribute__((ext_vector_type(4))) float;   // 4 fp32
using f32x16 = __attribute__((ext_vector_type(16))) float;  // 16 fp32
using u32x4  = __attribute__((ext_vector_type(4))) unsigned;

__device__ __forceinline__ unsigned short f2bf(float f){
  unsigned u = __float_as_uint(f);
  u += 0x7fffu + ((u>>16)&1u);          // RNE
  return (unsigned short)(u>>16);
}

__device__ __forceinline__ void gload_lds16(const void* g, void* l){
  __builtin_amdgcn_global_load_lds((const __attribute__((address_space(1))) void*)g,
                                   (__attribute__((address_space(3))) void*)l, 16, 0, 0);
}

__device__ __forceinline__ float fexp2(float x){
#if __has_builtin(__builtin_amdgcn_exp2f)
  return __builtin_amdgcn_exp2f(x);
#else
  return __expf(x * 0.69314718056f);
#endif
}

__device__ __forceinline__ unsigned cvtpk_bf16(float lo, float hi){
  unsigned r;
  asm("v_cvt_pk_bf16_f32 %0, %1, %2" : "=v"(r) : "v"(lo), "v"(hi));
  return r;
}

__device__ __forceinline__ void swap32(unsigned &a, unsigned &b){
#if __has_builtin(__builtin_amdgcn_permlane32_swap)
  auto rr = __builtin_amdgcn_permlane32_swap((int)a, (int)b, false, false);
  a = (unsigned)rr[0]; b = (unsigned)rr[1];
#else
  const bool lo = (threadIdx.x & 32) == 0;
  unsigned sa = (unsigned)__shfl_xor((int)a, 32, 64);
  unsigned sb = (unsigned)__shfl_xor((int)b, 32, 64);
  unsigned na = lo ? a : sb;
  unsigned nb = lo ? sa : b;
  a = na; b = nb;
#endif
}

__device__ __forceinline__ f32x16 mfma32(bf16x8 a, bf16x8 b, f32x16 c){
  return __builtin_amdgcn_mfma_f32_32x32x16_bf16(a, b, c, 0, 0, 0);
}

// ---------------- fused prep: all fp32->bf16 casts in ONE dispatch ----------------
__global__ __launch_bounds__(256) void prep_k(const float* __restrict__ Q, const float* __restrict__ K,
                                              const float* __restrict__ V, const float* __restrict__ Wq,
                                              const float* __restrict__ Wk, const float* __restrict__ Wv,
                                              const float* __restrict__ Wo,
                                              unsigned short* __restrict__ Xbf,
                                              unsigned short* __restrict__ Wbf){
  const int bid = blockIdx.x;
  const float* src; unsigned short* dst; int i;
  if (bid < 12288){
    const int which = bid >> 12;
    src = (which==0) ? Q : (which==1) ? K : V;
    dst = Xbf + ((size_t)which << 22);
    i = (bid & 4095)*256 + threadIdx.x;
  } else {
    const int which = (bid - 12288) >> 10;
    src = (which==0) ? Wq : (which==1) ? Wk : (which==2) ? Wv : Wo;
    dst = Wbf + ((size_t)which << 20);
    i = ((bid - 12288) & 1023)*256 + threadIdx.x;
  }
  float4 v = ((const float4*)src)[i];
  ushort4 o;
  o.x = f2bf(v.x); o.y = f2bf(v.y); o.z = f2bf(v.z); o.w = f2bf(v.w);
  ((ushort4*)dst)[i] = o;
}

// ---------------- QKV GEMM: BM=256 (2 m-subtiles), BN=128, BK=32, 4 waves ----------------
// 1-D grid 384 with chunked XCD remap: each XCD owns 48 consecutive logical blocks
// (6 m-panels' A footprint ~3MB -> L2-fits; was: every XCD read all 24MB of A).
__global__ __launch_bounds__(256) void gemm_qkv(const short* __restrict__ Xbf, const short* __restrict__ Wbf,
                                                unsigned short* __restrict__ qh, unsigned short* __restrict__ kh,
                                                unsigned short* __restrict__ vT){
  __shared__ short lsA[2][2][4096];   // [buf][msub][128 rows x 32 k]
  __shared__ short lsB[2][4096];
  const int tid = threadIdx.x;
  const int hw = blockIdx.x;                         // 384 blocks
  const int logical = (hw & 7)*48 + (hw >> 3);       // bijective (384 = 8*48)
  const int z = logical >> 7, rem = logical & 127;
  const int my = rem >> 3, nx = rem & 7;
  const short* A = Xbf + (size_t)z*NM*ND;
  const short* W = Wbf + (size_t)z*ND*ND;
  unsigned short* out = (z==0) ? qh : (z==1) ? kh : vT;
  const int mode = (z==2) ? 1 : 0;
  const int m0 = my*256, n0 = nx*128;

  const short* gA0 = A + (size_t)m0*1024;
  const short* gA1 = A + (size_t)(m0+128)*1024;
  const short* gB  = W + (size_t)n0*1024;
  const int srow = tid>>2, scol = (tid&3)*8;
  const int w = tid>>6, lane = tid&63, lr = lane&15, lk = lane>>4;
  const int wm = w>>1, wn = w&1;

  f32x4 acc0[4][4], acc1[4][4];
  #pragma unroll
  for (int i=0;i<4;++i)
    #pragma unroll
    for (int j=0;j<4;++j){ acc0[i][j] = (f32x4){0.f,0.f,0.f,0.f}; acc1[i][j] = (f32x4){0.f,0.f,0.f,0.f}; }

  // prologue: stage k-step 0 into buf 0
  #pragma unroll
  for (int r=0;r<2;++r){
    gload_lds16(gA0 + (size_t)(r*64+srow)*1024 + scol, &lsA[0][0][(r*256+tid)*8]);
    gload_lds16(gA1 + (size_t)(r*64+srow)*1024 + scol, &lsA[0][1][(r*256+tid)*8]);
    gload_lds16(gB  + (size_t)(r*64+srow)*1024 + scol, &lsB[0][(r*256+tid)*8]);
  }
  int cur = 0;
  for (int ks=0; ks<32; ++ks){
    __syncthreads();
    if (ks+1 < 32){
      const int k0 = (ks+1)*32;
      #pragma unroll
      for (int r=0;r<2;++r){
        gload_lds16(gA0 + (size_t)(r*64+srow)*1024 + k0 + scol, &lsA[cur^1][0][(r*256+tid)*8]);
        gload_lds16(gA1 + (size_t)(r*64+srow)*1024 + k0 + scol, &lsA[cur^1][1][(r*256+tid)*8]);
        gload_lds16(gB  + (size_t)(r*64+srow)*1024 + k0 + scol, &lsB[cur^1][(r*256+tid)*8]);
      }
    }
    bf16x8 bfr[4], af[4];
    #pragma unroll
    for (int j=0;j<4;++j) bfr[j] = *(const bf16x8*)&lsB[cur][(wn*64+j*16+lr)*32 + lk*8];
    #pragma unroll
    for (int i=0;i<4;++i) af[i] = *(const bf16x8*)&lsA[cur][0][(wm*64+i*16+lr)*32 + lk*8];
    #pragma unroll
    for (int i=0;i<4;++i)
      #pragma unroll
      for (int j=0;j<4;++j)
        acc0[i][j] = __builtin_amdgcn_mfma_f32_16x16x32_bf16(af[i], bfr[j], acc0[i][j], 0,0,0);
    #pragma unroll
    for (int i=0;i<4;++i) af[i] = *(const bf16x8*)&lsA[cur][1][(wm*64+i*16+lr)*32 + lk*8];
    #pragma unroll
    for (int i=0;i<4;++i)
      #pragma unroll
      for (int j=0;j<4;++j)
        acc1[i][j] = __builtin_amdgcn_mfma_f32_16x16x32_bf16(af[i], bfr[j], acc1[i][j], 0,0,0);
    cur ^= 1;
  }
  // epilogue x2 subtiles: C/D layout col=lane&15, row=(lane>>4)*4+r
  #pragma unroll
  for (int sub=0; sub<2; ++sub){
    const int mb = m0 + sub*128;
    #pragma unroll
    for (int i=0;i<4;++i)
      #pragma unroll
      for (int j=0;j<4;++j)
        #pragma unroll
        for (int r=0;r<4;++r){
          const int m = mb + wm*64 + i*16 + lk*4 + r;
          const int n = n0 + wn*64 + j*16 + lr;
          const float v = sub ? acc1[i][j][r] : acc0[i][j][r];
          const int b = m>>11, s = m&2047, h = n>>6, dk = n&63;
          size_t addr;
          if (mode == 0) addr = (((size_t)(b*NH+h))*NS + s)*NDK + dk;     // [b,h,s,dk]
          else           addr = (((size_t)(b*NH+h))*NDK + dk)*NS + s;     // [b,h,dk,s]
          out[addr] = f2bf(v);
        }
  }
}

// ---------------- output projection: 128x128 m97 core + fused residual ----------------
__global__ __launch_bounds__(256) void gemm_out(const short* __restrict__ Attn, const short* __restrict__ Wo,
                                                const float* __restrict__ Qin, float* __restrict__ proj){
  __shared__ short lsA[2][4096];
  __shared__ short lsB[2][4096];
  const int tid = threadIdx.x;
  const int hw = blockIdx.x;                        // 256 blocks
  const int logical = (hw & 7)*32 + (hw >> 3);      // bijective (256 = 8*32)
  const int my = logical >> 3, nx = logical & 7;
  const int m0 = my*128, n0 = nx*128;
  const short* gA = Attn + (size_t)m0*1024;
  const short* gB = Wo + (size_t)n0*1024;
  const int srow = tid>>2, scol = (tid&3)*8;
  const int w = tid>>6, lane = tid&63, lr = lane&15, lk = lane>>4;
  const int wm = w>>1, wn = w&1;

  f32x4 acc[4][4];
  #pragma unroll
  for (int i=0;i<4;++i)
    #pragma unroll
    for (int j=0;j<4;++j) acc[i][j] = (f32x4){0.f,0.f,0.f,0.f};

  #pragma unroll
  for (int r=0;r<2;++r){
    gload_lds16(gA + (size_t)(r*64+srow)*1024 + scol, &lsA[0][(r*256+tid)*8]);
    gload_lds16(gB + (size_t)(r*64+srow)*1024 + scol, &lsB[0][(r*256+tid)*8]);
  }
  int cur = 0;
  for (int ks=0; ks<32; ++ks){
    __syncthreads();
    if (ks+1 < 32){
      const int k0 = (ks+1)*32;
      #pragma unroll
      for (int r=0;r<2;++r){
        gload_lds16(gA + (size_t)(r*64+srow)*1024 + k0 + scol, &lsA[cur^1][(r*256+tid)*8]);
        gload_lds16(gB + (size_t)(r*64+srow)*1024 + k0 + scol, &lsB[cur^1][(r*256+tid)*8]);
      }
    }
    bf16x8 af[4], bfr[4];
    #pragma unroll
    for (int i=0;i<4;++i){
      af[i]  = *(const bf16x8*)&lsA[cur][(wm*64+i*16+lr)*32 + lk*8];
      bfr[i] = *(const bf16x8*)&lsB[cur][(wn*64+i*16+lr)*32 + lk*8];
    }
    #pragma unroll
    for (int i=0;i<4;++i)
      #pragma unroll
      for (int j=0;j<4;++j)
        acc[i][j] = __builtin_amdgcn_mfma_f32_16x16x32_bf16(af[i], bfr[j], acc[i][j], 0,0,0);
    cur ^= 1;
  }
  #pragma unroll
  for (int i=0;i<4;++i)
    #pragma unroll
    for (int j=0;j<4;++j)
      #pragma unroll
      for (int r=0;r<4;++r){
        const int m = m0 + wm*64 + i*16 + lk*4 + r;
        const int n = n0 + wn*64 + j*16 + lr;
        proj[(size_t)m*1024 + n] = acc[i][j][r] + Qin[(size_t)m*1024 + n];   // fused residual
      }
}

// ---------------- flash attention: LDS-staged double-buffered K/V ----------------
// Grid: 256 blocks = (b, h, qblk-of-256) -> 1 block/CU. 8 warps x 32 q rows.
__global__ __launch_bounds__(512) void attn_k(const short* __restrict__ qh, const short* __restrict__ kh,
                                              const short* __restrict__ vT, const int* __restrict__ mask,
                                              unsigned short* __restrict__ attn){
  __shared__ char sb[32768];   // K buf0 @0, K buf1 @8K, V buf0 @16K, V buf1 @24K; epilogue scratch after barrier
  const int bid = blockIdx.x;
  const int qb = bid & 7, h = (bid>>3)&15, b = bid>>7;
  const int tid = threadIdx.x, w = tid>>6, lane = tid&63;
  const int ql = lane & 31, hi = lane>>5;
  const int bh = b*NH + h;
  const int q0 = qb*256 + w*32;
  const float C2 = 0.18033688f;   // 0.125 * log2(e)

  // staging addressing: D = linear dest byte in 8KB tile; S = pre-swizzled source byte
  const int D = tid*16;
  const int strow = D>>7;                        // tile row (kv for K, dk for V)
  const int S = D ^ ((strow&7)<<4);
  const char* ksrc  = (const char*)(kh + (size_t)bh*NS*NDK) + S;                       // + kv0*128
  const char* vsrc  = (const char*)(vT + ((size_t)bh*NDK + strow)*NS) + (S & 127);     // + kv0*2

  // Q as B-fragments: lane holds Q[q0+ql][kp*16 + hi*8 + j]
  const short* qrow = qh + ((size_t)bh*NS + q0 + ql)*NDK + hi*8;
  bf16x8 qf[4];
  #pragma unroll
  for (int kp=0;kp<4;++kp) qf[kp] = *(const bf16x8*)(qrow + kp*16);

  const int* mrow = mask + b*NS;

  f32x16 o0, o1;
  #pragma unroll
  for (int r=0;r<16;++r){ o0[r]=0.f; o1[r]=0.f; }
  float mrun = -1e30f, lrun = 0.f;

  const int swz = (ql&7)<<4;

  // prologue: stage tile 0 into buf 0
  gload_lds16(ksrc, sb + D);
  gload_lds16(vsrc, sb + 16384 + D);

  for (int kt=0; kt<32; ++kt){
    const int kv0 = kt*64;
    const int buf = (kt&1)*8192;
    __syncthreads();
    if (kt+1 < 32){
      const int nbuf = ((kt+1)&1)*8192;
      gload_lds16(ksrc + (size_t)(kv0+64)*128, sb + nbuf + D);
      gload_lds16(vsrc + (size_t)(kv0+64)*2,   sb + 16384 + nbuf + D);
    }
    const unsigned long long bal = __ballot(mrow[kv0 + lane] != 0);
    const unsigned mw0 = (unsigned)bal, mw1 = (unsigned)(bal>>32);
    const bool allm = (~bal) == 0ull;

    bf16x8 kf[8];
    #pragma unroll
    for (int kvh=0;kvh<2;++kvh)
      #pragma unroll
      for (int kp=0;kp<4;++kp)
        kf[kvh*4+kp] = *(const bf16x8*)(sb + buf + (((kvh*32+ql)*128 + kp*32 + hi*16) ^ swz));

    f32x16 s0, s1;
    #pragma unroll
    for (int r=0;r<16;++r){ s0[r]=0.f; s1[r]=0.f; }
    #pragma unroll
    for (int kp=0;kp<4;++kp){
      s0 = mfma32(kf[kp],   qf[kp], s0);
      s1 = mfma32(kf[4+kp], qf[kp], s1);
    }

    float t[16];
    #pragma unroll
    for (int r=0;r<16;++r) t[r] = fmaxf(s0[r], s1[r]);
    #pragma unroll
    for (int st=8; st>=1; st>>=1)
      #pragma unroll
      for (int r=0;r<st;++r) t[r] = fmaxf(t[r], t[r+st]);
    const float tm = fmaxf(t[0], __shfl_xor(t[0], 32, 64));

    if (!__all(tm - mrun <= 32.f)){
      const float mnew = fmaxf(mrun, tm);
      const float fac  = fexp2((mrun - mnew)*C2);
      mrun = mnew;
      #pragma unroll
      for (int r=0;r<16;++r){ o0[r]*=fac; o1[r]*=fac; }
      lrun *= fac;
    }
    const float nb = mrun*C2;

    bf16x8 vf[8];
    #pragma unroll
    for (int dh=0;dh<2;++dh)
      #pragma unroll
      for (int c=0;c<4;++c)
        vf[dh*4+c] = *(const bf16x8*)(sb + 16384 + buf + (((dh*32+ql)*128 + c*32 + hi*16) ^ swz));

    float psum = 0.f;
    #pragma unroll
    for (int kvh=0; kvh<2; ++kvh){
      const f32x16& ss = kvh ? s1 : s0;
      const unsigned mw = kvh ? mw1 : mw0;
      unsigned pwd[8];
      float ps0 = 0.f, ps1 = 0.f;
      #pragma unroll
      for (int i=0;i<8;++i){
        const int bp0 = ((2*i)&3) + 8*((2*i)>>2);   // {0,2,8,10,16,18,24,26}
        float p0 = fexp2(ss[2*i]*C2   - nb);
        float p1 = fexp2(ss[2*i+1]*C2 - nb);
        if (!allm){
          p0 = ((mw >> (bp0     + 4*hi)) & 1u) ? p0 : 0.f;
          p1 = ((mw >> (bp0 + 1 + 4*hi)) & 1u) ? p1 : 0.f;
        }
        ps0 += p0; ps1 += p1;
        pwd[i] = cvtpk_bf16(p0, p1);
      }
      psum += ps0 + ps1;
      swap32(pwd[0], pwd[2]);
      swap32(pwd[1], pwd[3]);
      swap32(pwd[4], pwd[6]);
      swap32(pwd[5], pwd[7]);
      u32x4 c0w = {pwd[0], pwd[1], pwd[2], pwd[3]};
      u32x4 c1w = {pwd[4], pwd[5], pwd[6], pwd[7]};
      bf16x8 pf0 = __builtin_bit_cast(bf16x8, c0w);
      bf16x8 pf1 = __builtin_bit_cast(bf16x8, c1w);
      o0 = mfma32(vf[0*4 + 2*kvh],     pf0, o0);
      o1 = mfma32(vf[1*4 + 2*kvh],     pf0, o1);
      o0 = mfma32(vf[0*4 + 2*kvh + 1], pf1, o0);
      o1 = mfma32(vf[1*4 + 2*kvh + 1], pf1, o1);
    }
    psum += __shfl_xor(psum, 32, 64);
    lrun += psum;
  }

  // ---- epilogue: per-warp 4KB LDS transpose (reuse staging buffers) ----
  __syncthreads();
  const float inv = 1.f / lrun;
  char* ep = sb + w*4096;
  #pragma unroll
  for (int dh=0; dh<2; ++dh){
    const f32x16& oo = dh ? o1 : o0;
    #pragma unroll
    for (int i=0;i<8;++i){
      const int d0 = ((2*i)&3) + 8*((2*i)>>2) + 4*hi + dh*32;
      const unsigned pk = cvtpk_bf16(oo[2*i]*inv, oo[2*i+1]*inv);
      *(unsigned*)(ep + (((ql*128) + d0*2) ^ ((ql&7)<<4))) = pk;
    }
  }
  asm volatile("s_waitcnt lgkmcnt(0)" ::: "memory");
  #pragma unroll
  for (int seg=0; seg<4; ++seg){
    const int qq = seg*8 + (lane>>3), dc = (lane&7)*8;
    bf16x8 vv = *(const bf16x8*)(ep + (((qq*128) + dc*2) ^ ((qq&7)<<4)));
    *(bf16x8*)(attn + ((size_t)b*NS + q0 + qq)*ND + h*NDK + dc) = vv;
  }
}

// ---------------- LayerNorm (1 wave per row; residual already in proj) ----------------
__global__ __launch_bounds__(256) void ln_k(const float* __restrict__ proj,
                                            const float* __restrict__ gamma, const float* __restrict__ beta,
                                            float* __restrict__ out){
  const int row = blockIdx.x*4 + (threadIdx.x>>6);
  const int lane = threadIdx.x & 63;
  const float4* pp = (const float4*)(proj + (size_t)row*ND);
  float4 x[4];
  float sum = 0.f;
  #pragma unroll
  for (int i=0;i<4;++i){
    x[i] = pp[lane + i*64];
    sum += x[i].x + x[i].y + x[i].z + x[i].w;
  }
  #pragma unroll
  for (int off=32; off>=1; off>>=1) sum += __shfl_xor(sum, off, 64);
  const float mu = sum * (1.f/1024.f);
  float vs = 0.f;
  #pragma unroll
  for (int i=0;i<4;++i){
    float d0=x[i].x-mu, d1=x[i].y-mu, d2=x[i].z-mu, d3=x[i].w-mu;
    vs += d0*d0 + d1*d1 + d2*d2 + d3*d3;
  }
  #pragma unroll
  for (int off=32; off>=1; off>>=1) vs += __shfl_xor(vs, off, 64);
  const float rstd = rsqrtf(vs*(1.f/1024.f) + 1e-5f);
  #pragma unroll
  for (int i=0;i<4;++i){
    const float4 g  = ((const float4*)gamma)[lane + i*64];
    const float4 be = ((const float4*)beta)[lane + i*64];
    float4 y;
    y.x = (x[i].x-mu)*rstd*g.x + be.x;
    y.y = (x[i].y-mu)*rstd*g.y + be.y;
    y.z = (x[i].z-mu)*rstd*g.z + be.z;
    y.w = (x[i].w-mu)*rstd*g.w + be.w;
    ((float4*)(out + (size_t)row*ND))[lane + i*64] = y;
  }
}

// ---------------- launch ----------------
// ws layout (64 MB):
//   [0,8MB)   Wbf: Wq,Wk,Wv,Wo bf16
//   [8,32MB)  Xbf: Qbf,Kbf,Vbf ; later: proj f32 (16MB, after gemm_qkv)
//   [32,40)   qh bf16 [b,h,s,dk]
//   [40,48)   kh bf16 [b,h,s,dk]
//   [48,56)   vT bf16 [b,h,dk,s]
//   [56,64)   attn bf16 [b,s,d]
extern "C" void kernel_launch(void* const* d_in, const int* in_sizes, int n_in,
                              void* d_out, int out_size, void* d_ws, size_t ws_size,
                              hipStream_t stream){
  const float* Q    = (const float*)d_in[0];
  const float* K    = (const float*)d_in[1];
  const float* V    = (const float*)d_in[2];
  const int*   mask = (const int*)  d_in[3];
  const float* Wq   = (const float*)d_in[4];
  const float* Wk   = (const float*)d_in[5];
  const float* Wv   = (const float*)d_in[6];
  const float* Wo   = (const float*)d_in[7];
  const float* gam  = (const float*)d_in[8];
  const float* bet  = (const float*)d_in[9];
  float* out = (float*)d_out;
  char* ws = (char*)d_ws;

  unsigned short* Wbf  = (unsigned short*)(ws);
  unsigned short* Xbf  = (unsigned short*)(ws + (size_t)(8u<<20));
  unsigned short* qhp  = (unsigned short*)(ws + (size_t)(32u<<20));
  unsigned short* khp  = (unsigned short*)(ws + (size_t)(40u<<20));
  unsigned short* vTp  = (unsigned short*)(ws + (size_t)(48u<<20));
  unsigned short* attb = (unsigned short*)(ws + (size_t)(56u<<20));
  float* proj  = (float*)(ws + (size_t)(8u<<20));          // aliases Xbf (dead after gemm_qkv)

  prep_k<<<16384,256,0,stream>>>(Q, K, V, Wq, Wk, Wv, Wo, Xbf, Wbf);

  gemm_qkv<<<384,256,0,stream>>>((const short*)Xbf, (const short*)Wbf, qhp, khp, vTp);

  attn_k<<<256,512,0,stream>>>((const short*)qhp, (const short*)khp, (const short*)vTp, mask, attb);

  gemm_out<<<256,256,0,stream>>>((const short*)attb, (const short*)(Wbf + (3u<<20)), Q, proj);

  ln_k<<<1024,256,0,stream>>>(proj, gam, bet, out);
}

// Round 7
// 161.055 us; speedup vs baseline: 1.1148x; 1.1148x over previous
//
#include <hip/hip_runtime.h>
#include <hip/hip_bf16.h>
#include <stdint.h>

// Problem constants
#define NB 2
#define NS 2048
#define ND 1024
#define NH 16
#define NDK 64
#define NM (NB*NS)   // 4096 rows

using bf16x8 = __attribute__((ext_vector_type(8))) short;   // 8 bf16 (4 VGPRs)
using f32x4  = __attribute__((ext_vector_type(4))) float;   // 4 fp32
using f32x16 = __attribute__((ext_vector_type(16))) float;  // 16 fp32
using u32x4  = __attribute__((ext_vector_type(4))) unsigned;

__device__ __forceinline__ unsigned short f2bf(float f){
  unsigned u = __float_as_uint(f);
  u += 0x7fffu + ((u>>16)&1u);          // RNE
  return (unsigned short)(u>>16);
}

__device__ __forceinline__ void gload_lds16(const void* g, void* l){
  __builtin_amdgcn_global_load_lds((const __attribute__((address_space(1))) void*)g,
                                   (__attribute__((address_space(3))) void*)l, 16, 0, 0);
}

__device__ __forceinline__ float fexp2(float x){
#if __has_builtin(__builtin_amdgcn_exp2f)
  return __builtin_amdgcn_exp2f(x);
#else
  return __expf(x * 0.69314718056f);
#endif
}

__device__ __forceinline__ unsigned cvtpk_bf16(float lo, float hi){
  unsigned r;
  asm("v_cvt_pk_bf16_f32 %0, %1, %2" : "=v"(r) : "v"(lo), "v"(hi));
  return r;
}

__device__ __forceinline__ void swap32(unsigned &a, unsigned &b){
#if __has_builtin(__builtin_amdgcn_permlane32_swap)
  auto rr = __builtin_amdgcn_permlane32_swap((int)a, (int)b, false, false);
  a = (unsigned)rr[0]; b = (unsigned)rr[1];
#else
  const bool lo = (threadIdx.x & 32) == 0;
  unsigned sa = (unsigned)__shfl_xor((int)a, 32, 64);
  unsigned sb = (unsigned)__shfl_xor((int)b, 32, 64);
  unsigned na = lo ? a : sb;
  unsigned nb = lo ? sa : b;
  a = na; b = nb;
#endif
}

__device__ __forceinline__ f32x16 mfma32(bf16x8 a, bf16x8 b, f32x16 c){
  return __builtin_amdgcn_mfma_f32_32x32x16_bf16(a, b, c, 0, 0, 0);
}

// ---------------- fused prep: all fp32->bf16 casts in ONE dispatch ----------------
__global__ __launch_bounds__(256) void prep_k(const float* __restrict__ Q, const float* __restrict__ K,
                                              const float* __restrict__ V, const float* __restrict__ Wq,
                                              const float* __restrict__ Wk, const float* __restrict__ Wv,
                                              const float* __restrict__ Wo,
                                              unsigned short* __restrict__ Xbf,
                                              unsigned short* __restrict__ Wbf){
  const int bid = blockIdx.x;
  const float* src; unsigned short* dst; int i;
  if (bid < 12288){
    const int which = bid >> 12;
    src = (which==0) ? Q : (which==1) ? K : V;
    dst = Xbf + ((size_t)which << 22);
    i = (bid & 4095)*256 + threadIdx.x;
  } else {
    const int which = (bid - 12288) >> 10;
    src = (which==0) ? Wq : (which==1) ? Wk : (which==2) ? Wv : Wo;
    dst = Wbf + ((size_t)which << 20);
    i = ((bid - 12288) & 1023)*256 + threadIdx.x;
  }
  float4 v = ((const float4*)src)[i];
  ushort4 o;
  o.x = f2bf(v.x); o.y = f2bf(v.y); o.z = f2bf(v.z); o.w = f2bf(v.w);
  ((ushort4*)dst)[i] = o;
}

// ---------------- QKV GEMM: 128x128 m97 core, 768 blocks, XCD-chunked remap ----------------
// R7 config: R5's concurrency (768 blocks -> 3 blocks/CU co-resident, m114 overlap)
// + R6's bijective XCD remap (per-XCD: 12 m-panels A ~3MB + one W ~2MB -> L2-fits).
__global__ __launch_bounds__(256) void gemm_qkv(const short* __restrict__ Xbf, const short* __restrict__ Wbf,
                                                unsigned short* __restrict__ qh, unsigned short* __restrict__ kh,
                                                unsigned short* __restrict__ vT){
  __shared__ short lsA[2][4096];
  __shared__ short lsB[2][4096];
  const int tid = threadIdx.x;
  const int hw = blockIdx.x;                         // 768 blocks
  const int logical = (hw & 7)*96 + (hw >> 3);       // bijective (768 = 8*96)
  const int z = logical >> 8, rem = logical & 255;
  const int my = rem >> 3, nx = rem & 7;
  const short* A = Xbf + (size_t)z*NM*ND;
  const short* W = Wbf + (size_t)z*ND*ND;
  unsigned short* out = (z==0) ? qh : (z==1) ? kh : vT;
  const int mode = (z==2) ? 1 : 0;
  const int m0 = my*128, n0 = nx*128;

  const short* gA = A + (size_t)m0*1024;
  const short* gB = W + (size_t)n0*1024;
  const int srow = tid>>2, scol = (tid&3)*8;
  const int w = tid>>6, lane = tid&63, lr = lane&15, lk = lane>>4;
  const int wm = w>>1, wn = w&1;

  f32x4 acc[4][4];
  #pragma unroll
  for (int i=0;i<4;++i)
    #pragma unroll
    for (int j=0;j<4;++j) acc[i][j] = (f32x4){0.f,0.f,0.f,0.f};

  #pragma unroll
  for (int r=0;r<2;++r){
    gload_lds16(gA + (size_t)(r*64+srow)*1024 + scol, &lsA[0][(r*256+tid)*8]);
    gload_lds16(gB + (size_t)(r*64+srow)*1024 + scol, &lsB[0][(r*256+tid)*8]);
  }
  int cur = 0;
  for (int ks=0; ks<32; ++ks){
    __syncthreads();
    if (ks+1 < 32){
      const int k0 = (ks+1)*32;
      #pragma unroll
      for (int r=0;r<2;++r){
        gload_lds16(gA + (size_t)(r*64+srow)*1024 + k0 + scol, &lsA[cur^1][(r*256+tid)*8]);
        gload_lds16(gB + (size_t)(r*64+srow)*1024 + k0 + scol, &lsB[cur^1][(r*256+tid)*8]);
      }
    }
    bf16x8 af[4], bfr[4];
    #pragma unroll
    for (int i=0;i<4;++i){
      af[i]  = *(const bf16x8*)&lsA[cur][(wm*64+i*16+lr)*32 + lk*8];
      bfr[i] = *(const bf16x8*)&lsB[cur][(wn*64+i*16+lr)*32 + lk*8];
    }
    #pragma unroll
    for (int i=0;i<4;++i)
      #pragma unroll
      for (int j=0;j<4;++j)
        acc[i][j] = __builtin_amdgcn_mfma_f32_16x16x32_bf16(af[i], bfr[j], acc[i][j], 0,0,0);
    cur ^= 1;
  }
  // epilogue: C/D layout col=lane&15, row=(lane>>4)*4+r
  #pragma unroll
  for (int i=0;i<4;++i)
    #pragma unroll
    for (int j=0;j<4;++j)
      #pragma unroll
      for (int r=0;r<4;++r){
        const int m = m0 + wm*64 + i*16 + lk*4 + r;
        const int n = n0 + wn*64 + j*16 + lr;
        const float v = acc[i][j][r];
        const int b = m>>11, s = m&2047, h = n>>6, dk = n&63;
        size_t addr;
        if (mode == 0) addr = (((size_t)(b*NH+h))*NS + s)*NDK + dk;     // [b,h,s,dk]
        else           addr = (((size_t)(b*NH+h))*NDK + dk)*NS + s;     // [b,h,dk,s]
        out[addr] = f2bf(v);
      }
}

// ---------------- output projection: 128x128 m97 core + fused residual ----------------
__global__ __launch_bounds__(256) void gemm_out(const short* __restrict__ Attn, const short* __restrict__ Wo,
                                                const float* __restrict__ Qin, float* __restrict__ proj){
  __shared__ short lsA[2][4096];
  __shared__ short lsB[2][4096];
  const int tid = threadIdx.x;
  const int hw = blockIdx.x;                        // 256 blocks
  const int logical = (hw & 7)*32 + (hw >> 3);      // bijective (256 = 8*32)
  const int my = logical >> 3, nx = logical & 7;
  const int m0 = my*128, n0 = nx*128;
  const short* gA = Attn + (size_t)m0*1024;
  const short* gB = Wo + (size_t)n0*1024;
  const int srow = tid>>2, scol = (tid&3)*8;
  const int w = tid>>6, lane = tid&63, lr = lane&15, lk = lane>>4;
  const int wm = w>>1, wn = w&1;

  f32x4 acc[4][4];
  #pragma unroll
  for (int i=0;i<4;++i)
    #pragma unroll
    for (int j=0;j<4;++j) acc[i][j] = (f32x4){0.f,0.f,0.f,0.f};

  #pragma unroll
  for (int r=0;r<2;++r){
    gload_lds16(gA + (size_t)(r*64+srow)*1024 + scol, &lsA[0][(r*256+tid)*8]);
    gload_lds16(gB + (size_t)(r*64+srow)*1024 + scol, &lsB[0][(r*256+tid)*8]);
  }
  int cur = 0;
  for (int ks=0; ks<32; ++ks){
    __syncthreads();
    if (ks+1 < 32){
      const int k0 = (ks+1)*32;
      #pragma unroll
      for (int r=0;r<2;++r){
        gload_lds16(gA + (size_t)(r*64+srow)*1024 + k0 + scol, &lsA[cur^1][(r*256+tid)*8]);
        gload_lds16(gB + (size_t)(r*64+srow)*1024 + k0 + scol, &lsB[cur^1][(r*256+tid)*8]);
      }
    }
    bf16x8 af[4], bfr[4];
    #pragma unroll
    for (int i=0;i<4;++i){
      af[i]  = *(const bf16x8*)&lsA[cur][(wm*64+i*16+lr)*32 + lk*8];
      bfr[i] = *(const bf16x8*)&lsB[cur][(wn*64+i*16+lr)*32 + lk*8];
    }
    #pragma unroll
    for (int i=0;i<4;++i)
      #pragma unroll
      for (int j=0;j<4;++j)
        acc[i][j] = __builtin_amdgcn_mfma_f32_16x16x32_bf16(af[i], bfr[j], acc[i][j], 0,0,0);
    cur ^= 1;
  }
  #pragma unroll
  for (int i=0;i<4;++i)
    #pragma unroll
    for (int j=0;j<4;++j)
      #pragma unroll
      for (int r=0;r<4;++r){
        const int m = m0 + wm*64 + i*16 + lk*4 + r;
        const int n = n0 + wn*64 + j*16 + lr;
        proj[(size_t)m*1024 + n] = acc[i][j][r] + Qin[(size_t)m*1024 + n];   // fused residual
      }
}

// ---------------- flash attention: LDS-staged double-buffered K/V ----------------
// Grid: 256 blocks = (b, h, qblk-of-256) -> 1 block/CU. 8 warps x 32 q rows.
__global__ __launch_bounds__(512) void attn_k(const short* __restrict__ qh, const short* __restrict__ kh,
                                              const short* __restrict__ vT, const int* __restrict__ mask,
                                              unsigned short* __restrict__ attn){
  __shared__ char sb[32768];   // K buf0 @0, K buf1 @8K, V buf0 @16K, V buf1 @24K; epilogue scratch after barrier
  const int bid = blockIdx.x;
  const int qb = bid & 7, h = (bid>>3)&15, b = bid>>7;
  const int tid = threadIdx.x, w = tid>>6, lane = tid&63;
  const int ql = lane & 31, hi = lane>>5;
  const int bh = b*NH + h;
  const int q0 = qb*256 + w*32;
  const float C2 = 0.18033688f;   // 0.125 * log2(e)

  // staging addressing: D = linear dest byte in 8KB tile; S = pre-swizzled source byte
  const int D = tid*16;
  const int strow = D>>7;                        // tile row (kv for K, dk for V)
  const int S = D ^ ((strow&7)<<4);
  const char* ksrc  = (const char*)(kh + (size_t)bh*NS*NDK) + S;                       // + kv0*128
  const char* vsrc  = (const char*)(vT + ((size_t)bh*NDK + strow)*NS) + (S & 127);     // + kv0*2

  // Q as B-fragments: lane holds Q[q0+ql][kp*16 + hi*8 + j]
  const short* qrow = qh + ((size_t)bh*NS + q0 + ql)*NDK + hi*8;
  bf16x8 qf[4];
  #pragma unroll
  for (int kp=0;kp<4;++kp) qf[kp] = *(const bf16x8*)(qrow + kp*16);

  const int* mrow = mask + b*NS;

  f32x16 o0, o1;
  #pragma unroll
  for (int r=0;r<16;++r){ o0[r]=0.f; o1[r]=0.f; }
  float mrun = -1e30f, lrun = 0.f;

  const int swz = (ql&7)<<4;

  // prologue: stage tile 0 into buf 0
  gload_lds16(ksrc, sb + D);
  gload_lds16(vsrc, sb + 16384 + D);

  for (int kt=0; kt<32; ++kt){
    const int kv0 = kt*64;
    const int buf = (kt&1)*8192;
    __syncthreads();
    if (kt+1 < 32){
      const int nbuf = ((kt+1)&1)*8192;
      gload_lds16(ksrc + (size_t)(kv0+64)*128, sb + nbuf + D);
      gload_lds16(vsrc + (size_t)(kv0+64)*2,   sb + 16384 + nbuf + D);
    }
    const unsigned long long bal = __ballot(mrow[kv0 + lane] != 0);
    const unsigned mw0 = (unsigned)bal, mw1 = (unsigned)(bal>>32);
    const bool allm = (~bal) == 0ull;

    bf16x8 kf[8];
    #pragma unroll
    for (int kvh=0;kvh<2;++kvh)
      #pragma unroll
      for (int kp=0;kp<4;++kp)
        kf[kvh*4+kp] = *(const bf16x8*)(sb + buf + (((kvh*32+ql)*128 + kp*32 + hi*16) ^ swz));

    f32x16 s0, s1;
    #pragma unroll
    for (int r=0;r<16;++r){ s0[r]=0.f; s1[r]=0.f; }
    #pragma unroll
    for (int kp=0;kp<4;++kp){
      s0 = mfma32(kf[kp],   qf[kp], s0);
      s1 = mfma32(kf[4+kp], qf[kp], s1);
    }

    float t[16];
    #pragma unroll
    for (int r=0;r<16;++r) t[r] = fmaxf(s0[r], s1[r]);
    #pragma unroll
    for (int st=8; st>=1; st>>=1)
      #pragma unroll
      for (int r=0;r<st;++r) t[r] = fmaxf(t[r], t[r+st]);
    const float tm = fmaxf(t[0], __shfl_xor(t[0], 32, 64));

    if (!__all(tm - mrun <= 32.f)){
      const float mnew = fmaxf(mrun, tm);
      const float fac  = fexp2((mrun - mnew)*C2);
      mrun = mnew;
      #pragma unroll
      for (int r=0;r<16;++r){ o0[r]*=fac; o1[r]*=fac; }
      lrun *= fac;
    }
    const float nb = mrun*C2;

    bf16x8 vf[8];
    #pragma unroll
    for (int dh=0;dh<2;++dh)
      #pragma unroll
      for (int c=0;c<4;++c)
        vf[dh*4+c] = *(const bf16x8*)(sb + 16384 + buf + (((dh*32+ql)*128 + c*32 + hi*16) ^ swz));

    float psum = 0.f;
    #pragma unroll
    for (int kvh=0; kvh<2; ++kvh){
      const f32x16& ss = kvh ? s1 : s0;
      const unsigned mw = kvh ? mw1 : mw0;
      unsigned pwd[8];
      float ps0 = 0.f, ps1 = 0.f;
      #pragma unroll
      for (int i=0;i<8;++i){
        const int bp0 = ((2*i)&3) + 8*((2*i)>>2);   // {0,2,8,10,16,18,24,26}
        float p0 = fexp2(ss[2*i]*C2   - nb);
        float p1 = fexp2(ss[2*i+1]*C2 - nb);
        if (!allm){
          p0 = ((mw >> (bp0     + 4*hi)) & 1u) ? p0 : 0.f;
          p1 = ((mw >> (bp0 + 1 + 4*hi)) & 1u) ? p1 : 0.f;
        }
        ps0 += p0; ps1 += p1;
        pwd[i] = cvtpk_bf16(p0, p1);
      }
      psum += ps0 + ps1;
      swap32(pwd[0], pwd[2]);
      swap32(pwd[1], pwd[3]);
      swap32(pwd[4], pwd[6]);
      swap32(pwd[5], pwd[7]);
      u32x4 c0w = {pwd[0], pwd[1], pwd[2], pwd[3]};
      u32x4 c1w = {pwd[4], pwd[5], pwd[6], pwd[7]};
      bf16x8 pf0 = __builtin_bit_cast(bf16x8, c0w);
      bf16x8 pf1 = __builtin_bit_cast(bf16x8, c1w);
      o0 = mfma32(vf[0*4 + 2*kvh],     pf0, o0);
      o1 = mfma32(vf[1*4 + 2*kvh],     pf0, o1);
      o0 = mfma32(vf[0*4 + 2*kvh + 1], pf1, o0);
      o1 = mfma32(vf[1*4 + 2*kvh + 1], pf1, o1);
    }
    psum += __shfl_xor(psum, 32, 64);
    lrun += psum;
  }

  // ---- epilogue: per-warp 4KB LDS transpose (reuse staging buffers) ----
  __syncthreads();
  const float inv = 1.f / lrun;
  char* ep = sb + w*4096;
  #pragma unroll
  for (int dh=0; dh<2; ++dh){
    const f32x16& oo = dh ? o1 : o0;
    #pragma unroll
    for (int i=0;i<8;++i){
      const int d0 = ((2*i)&3) + 8*((2*i)>>2) + 4*hi + dh*32;
      const unsigned pk = cvtpk_bf16(oo[2*i]*inv, oo[2*i+1]*inv);
      *(unsigned*)(ep + (((ql*128) + d0*2) ^ ((ql&7)<<4))) = pk;
    }
  }
  asm volatile("s_waitcnt lgkmcnt(0)" ::: "memory");
  #pragma unroll
  for (int seg=0; seg<4; ++seg){
    const int qq = seg*8 + (lane>>3), dc = (lane&7)*8;
    bf16x8 vv = *(const bf16x8*)(ep + (((qq*128) + dc*2) ^ ((qq&7)<<4)));
    *(bf16x8*)(attn + ((size_t)b*NS + q0 + qq)*ND + h*NDK + dc) = vv;
  }
}

// ---------------- LayerNorm (1 wave per row; residual already in proj) ----------------
__global__ __launch_bounds__(256) void ln_k(const float* __restrict__ proj,
                                            const float* __restrict__ gamma, const float* __restrict__ beta,
                                            float* __restrict__ out){
  const int row = blockIdx.x*4 + (threadIdx.x>>6);
  const int lane = threadIdx.x & 63;
  const float4* pp = (const float4*)(proj + (size_t)row*ND);
  float4 x[4];
  float sum = 0.f;
  #pragma unroll
  for (int i=0;i<4;++i){
    x[i] = pp[lane + i*64];
    sum += x[i].x + x[i].y + x[i].z + x[i].w;
  }
  #pragma unroll
  for (int off=32; off>=1; off>>=1) sum += __shfl_xor(sum, off, 64);
  const float mu = sum * (1.f/1024.f);
  float vs = 0.f;
  #pragma unroll
  for (int i=0;i<4;++i){
    float d0=x[i].x-mu, d1=x[i].y-mu, d2=x[i].z-mu, d3=x[i].w-mu;
    vs += d0*d0 + d1*d1 + d2*d2 + d3*d3;
  }
  #pragma unroll
  for (int off=32; off>=1; off>>=1) vs += __shfl_xor(vs, off, 64);
  const float rstd = rsqrtf(vs*(1.f/1024.f) + 1e-5f);
  #pragma unroll
  for (int i=0;i<4;++i){
    const float4 g  = ((const float4*)gamma)[lane + i*64];
    const float4 be = ((const float4*)beta)[lane + i*64];
    float4 y;
    y.x = (x[i].x-mu)*rstd*g.x + be.x;
    y.y = (x[i].y-mu)*rstd*g.y + be.y;
    y.z = (x[i].z-mu)*rstd*g.z + be.z;
    y.w = (x[i].w-mu)*rstd*g.w + be.w;
    ((float4*)(out + (size_t)row*ND))[lane + i*64] = y;
  }
}

// ---------------- launch ----------------
// ws layout (64 MB):
//   [0,8MB)   Wbf: Wq,Wk,Wv,Wo bf16
//   [8,32MB)  Xbf: Qbf,Kbf,Vbf ; later: proj f32 (16MB, after gemm_qkv)
//   [32,40)   qh bf16 [b,h,s,dk]
//   [40,48)   kh bf16 [b,h,s,dk]
//   [48,56)   vT bf16 [b,h,dk,s]
//   [56,64)   attn bf16 [b,s,d]
extern "C" void kernel_launch(void* const* d_in, const int* in_sizes, int n_in,
                              void* d_out, int out_size, void* d_ws, size_t ws_size,
                              hipStream_t stream){
  const float* Q    = (const float*)d_in[0];
  const float* K    = (const float*)d_in[1];
  const float* V    = (const float*)d_in[2];
  const int*   mask = (const int*)  d_in[3];
  const float* Wq   = (const float*)d_in[4];
  const float* Wk   = (const float*)d_in[5];
  const float* Wv   = (const float*)d_in[6];
  const float* Wo   = (const float*)d_in[7];
  const float* gam  = (const float*)d_in[8];
  const float* bet  = (const float*)d_in[9];
  float* out = (float*)d_out;
  char* ws = (char*)d_ws;

  unsigned short* Wbf  = (unsigned short*)(ws);
  unsigned short* Xbf  = (unsigned short*)(ws + (size_t)(8u<<20));
  unsigned short* qhp  = (unsigned short*)(ws + (size_t)(32u<<20));
  unsigned short* khp  = (unsigned short*)(ws + (size_t)(40u<<20));
  unsigned short* vTp  = (unsigned short*)(ws + (size_t)(48u<<20));
  unsigned short* attb = (unsigned short*)(ws + (size_t)(56u<<20));
  float* proj  = (float*)(ws + (size_t)(8u<<20));          // aliases Xbf (dead after gemm_qkv)

  prep_k<<<16384,256,0,stream>>>(Q, K, V, Wq, Wk, Wv, Wo, Xbf, Wbf);

  gemm_qkv<<<768,256,0,stream>>>((const short*)Xbf, (const short*)Wbf, qhp, khp, vTp);

  attn_k<<<256,512,0,stream>>>((const short*)qhp, (const short*)khp, (const short*)vTp, mask, attb);

  gemm_out<<<256,256,0,stream>>>((const short*)attb, (const short*)(Wbf + (3u<<20)), Q, proj);

  ln_k<<<1024,256,0,stream>>>(proj, gam, bet, out);
}